// Round 1
// baseline (387.157 us; speedup 1.0000x reference)
//
#include <hip/hip_runtime.h>
#include <math.h>

#define D_MODEL 16
#define D_FF 32
#define T 64
#define EPS 1e-5f

// LDS param-block offsets (floats)
#define P_G1 0
#define P_B1 (D_MODEL)
#define P_G2 (2*D_MODEL)
#define P_B2 (3*D_MODEL)
#define P_BF1 (4*D_MODEL)
#define P_BF2 (4*D_MODEL + D_FF)
#define P_TOTAL (5*D_MODEL + D_FF)

__global__ __launch_bounds__(64)
void transformer_block_kernel(
    const float* __restrict__ x,
    const float* __restrict__ Wk,
    const float* __restrict__ Wq,
    const float* __restrict__ Wv,
    const float* __restrict__ ln1_g, const float* __restrict__ ln1_b,
    const float* __restrict__ ln2_g, const float* __restrict__ ln2_b,
    const float* __restrict__ W1, const float* __restrict__ b1,
    const float* __restrict__ W2, const float* __restrict__ b2,
    float* __restrict__ out)
{
    __shared__ float sWq[D_MODEL*D_MODEL];
    __shared__ float sWk[D_MODEL*D_MODEL];
    __shared__ float sWv[D_MODEL*D_MODEL];
    __shared__ float sW1[D_MODEL*D_FF];
    __shared__ float sW2[D_FF*D_MODEL];
    __shared__ float sP[P_TOTAL];
    __shared__ float sK[T][D_MODEL];
    __shared__ float sV[T][D_MODEL];

    const int t = threadIdx.x;                       // token index, 0..63
    const size_t base = (size_t)blockIdx.x * (T * D_MODEL);

    // ---- stage weights/params into LDS (lane-uniform broadcast reads later)
    for (int i = t; i < D_MODEL*D_MODEL; i += 64) {
        sWq[i] = Wq[i]; sWk[i] = Wk[i]; sWv[i] = Wv[i];
    }
    for (int i = t; i < D_MODEL*D_FF; i += 64) {
        sW1[i] = W1[i]; sW2[i] = W2[i];
    }
    if (t < D_MODEL) {
        sP[P_G1 + t]  = ln1_g[t];
        sP[P_B1 + t]  = ln1_b[t];
        sP[P_G2 + t]  = ln2_g[t];
        sP[P_B2 + t]  = ln2_b[t];
        sP[P_BF2 + t] = b2[t];
    }
    if (t < D_FF) sP[P_BF1 + t] = b1[t];

    // ---- load this token's 16-float row (4x float4, 64B-aligned)
    float xr[D_MODEL];
    const float4* xp4 = (const float4*)(x + base + (size_t)t * D_MODEL);
    #pragma unroll
    for (int j = 0; j < D_MODEL/4; ++j) {
        float4 v4 = xp4[j];
        xr[4*j+0] = v4.x; xr[4*j+1] = v4.y; xr[4*j+2] = v4.z; xr[4*j+3] = v4.w;
    }

    // ---- LN1 stats (per-lane, channel dim fully resident)
    float mu = 0.f;
    #pragma unroll
    for (int j = 0; j < D_MODEL; ++j) mu += xr[j];
    mu *= (1.f / D_MODEL);
    float var = 0.f;
    #pragma unroll
    for (int j = 0; j < D_MODEL; ++j) { float d = xr[j] - mu; var += d*d; }
    var *= (1.f / D_MODEL);
    float rstd = rsqrtf(var + EPS);

    __syncthreads();   // weights/params staged

    float h[D_MODEL];
    #pragma unroll
    for (int j = 0; j < D_MODEL; ++j)
        h[j] = (xr[j] - mu) * rstd * sP[P_G1 + j] + sP[P_B1 + j];

    // ---- projections: q in regs, k/v to LDS
    float q[D_MODEL];
    #pragma unroll
    for (int j = 0; j < D_MODEL; ++j) {
        float aq = 0.f, ak = 0.f, av = 0.f;
        #pragma unroll
        for (int i = 0; i < D_MODEL; ++i) {
            float hi = h[i];
            aq += hi * sWq[i*D_MODEL + j];
            ak += hi * sWk[i*D_MODEL + j];
            av += hi * sWv[i*D_MODEL + j];
        }
        q[j] = aq;
        sK[t][j] = ak;
        sV[t][j] = av;
    }
    __syncthreads();

    // ---- causal attention, online softmax (sK/sV reads are lane-uniform)
    float m = -1e30f, l = 0.f;
    float y[D_MODEL];
    #pragma unroll
    for (int j = 0; j < D_MODEL; ++j) y[j] = 0.f;
    const float scale = 0.25f;   // 1/sqrt(D_MODEL)

    #pragma unroll 4
    for (int s = 0; s < T; ++s) {
        float sc = 0.f;
        #pragma unroll
        for (int j = 0; j < D_MODEL; ++j) sc += q[j] * sK[s][j];
        sc *= scale;
        if (s > t) sc = -1e30f;          // causal mask
        float mn = fmaxf(m, sc);
        float alpha = __expf(m - mn);    // 1 when m unchanged; 0 on first real step
        float p     = __expf(sc - mn);   // 0 for masked s
        l = l * alpha + p;
        #pragma unroll
        for (int j = 0; j < D_MODEL; ++j)
            y[j] = y[j] * alpha + p * sV[s][j];
        m = mn;
    }
    float rl = 1.f / l;

    // ---- residual 1
    #pragma unroll
    for (int j = 0; j < D_MODEL; ++j) xr[j] += y[j] * rl;

    // ---- LN2
    mu = 0.f;
    #pragma unroll
    for (int j = 0; j < D_MODEL; ++j) mu += xr[j];
    mu *= (1.f / D_MODEL);
    var = 0.f;
    #pragma unroll
    for (int j = 0; j < D_MODEL; ++j) { float d = xr[j] - mu; var += d*d; }
    var *= (1.f / D_MODEL);
    rstd = rsqrtf(var + EPS);

    float h2[D_MODEL];
    #pragma unroll
    for (int j = 0; j < D_MODEL; ++j)
        h2[j] = (xr[j] - mu) * rstd * sP[P_G2 + j] + sP[P_B2 + j];

    // ---- FFN fused: per hidden unit f, accumulate into o[16]
    float o[D_MODEL];
    #pragma unroll
    for (int j = 0; j < D_MODEL; ++j) o[j] = sP[P_BF2 + j];   // b2

    for (int f = 0; f < D_FF; ++f) {
        float u = sP[P_BF1 + f];
        #pragma unroll
        for (int j = 0; j < D_MODEL; ++j) u += h2[j] * sW1[j*D_FF + f];
        float g = 0.5f * u * (1.f + erff(u * 0.70710678118654752f));  // exact gelu
        #pragma unroll
        for (int j = 0; j < D_MODEL; ++j) o[j] += g * sW2[f*D_MODEL + j];
    }

    // ---- residual 2 + store (4x float4)
    float4* op4 = (float4*)(out + base + (size_t)t * D_MODEL);
    #pragma unroll
    for (int j = 0; j < D_MODEL/4; ++j) {
        float4 v4;
        v4.x = xr[4*j+0] + o[4*j+0];
        v4.y = xr[4*j+1] + o[4*j+1];
        v4.z = xr[4*j+2] + o[4*j+2];
        v4.w = xr[4*j+3] + o[4*j+3];
        op4[j] = v4;
    }
}

extern "C" void kernel_launch(void* const* d_in, const int* in_sizes, int n_in,
                              void* d_out, int out_size, void* d_ws, size_t ws_size,
                              hipStream_t stream) {
    const float* x     = (const float*)d_in[0];
    const float* Wk    = (const float*)d_in[1];
    const float* Wq    = (const float*)d_in[2];
    const float* Wv    = (const float*)d_in[3];
    const float* ln1_g = (const float*)d_in[4];
    const float* ln1_b = (const float*)d_in[5];
    const float* ln2_g = (const float*)d_in[6];
    const float* ln2_b = (const float*)d_in[7];
    const float* W1    = (const float*)d_in[8];
    const float* b1    = (const float*)d_in[9];
    const float* W2    = (const float*)d_in[10];
    const float* b2    = (const float*)d_in[11];
    float* out = (float*)d_out;

    const int n_blocks = in_sizes[0] / (T * D_MODEL);   // 16384
    transformer_block_kernel<<<n_blocks, 64, 0, stream>>>(
        x, Wk, Wq, Wv, ln1_g, ln1_b, ln2_g, ln2_b, W1, b1, W2, b2, out);
}

// Round 2
// 274.631 us; speedup vs baseline: 1.4097x; 1.4097x over previous
//
#include <hip/hip_runtime.h>
#include <math.h>

#define D_MODEL 16
#define D_FF 32
#define T 64
#define EPS 1e-5f
#define WAVES 4          // batch-blocks per 256-thread workgroup (1 per wave)

__device__ __forceinline__ float fast_rcp(float x) { return __builtin_amdgcn_rcpf(x); }

// exact-gelu via Abramowitz-Stegun 7.1.26 erf (max err 1.5e-7), branch-free
__device__ __forceinline__ float gelu_exact(float u) {
    float z  = fabsf(u) * 0.70710678118654752f;     // |u|/sqrt(2)
    float tt = fast_rcp(1.f + 0.3275911f * z);
    float poly = ((((1.061405429f * tt - 1.453152027f) * tt + 1.421413741f) * tt
                   - 0.284496736f) * tt + 0.254829592f) * tt;
    float erfz = 1.f - poly * __expf(-z * z);
    float er   = copysignf(erfz, u);
    return 0.5f * u * (1.f + er);
}

__global__ __launch_bounds__(256, 4)
void transformer_block_kernel(
    const float* __restrict__ x,
    const float* __restrict__ Wk,
    const float* __restrict__ Wq,
    const float* __restrict__ Wv,
    const float* __restrict__ ln1_g, const float* __restrict__ ln1_b,
    const float* __restrict__ ln2_g, const float* __restrict__ ln2_b,
    const float* __restrict__ W1, const float* __restrict__ b1,
    const float* __restrict__ W2, const float* __restrict__ b2,
    float* __restrict__ out)
{
    __shared__ float sWq[D_MODEL*D_MODEL];
    __shared__ float sWk[D_MODEL*D_MODEL];
    __shared__ float sWv[D_MODEL*D_MODEL];
    __shared__ float sW1[D_MODEL*D_FF];
    __shared__ float sW2[D_FF*D_MODEL];
    __shared__ float sG1[D_MODEL], sB1[D_MODEL], sG2[D_MODEL], sB2[D_MODEL];
    __shared__ float sBF1[D_FF], sBF2[D_MODEL];
    __shared__ float sK[WAVES][T][D_MODEL];
    __shared__ float sV[WAVES][T][D_MODEL];

    const int tid = threadIdx.x;
    const int w   = tid >> 6;          // wave id in workgroup
    const int t   = tid & 63;          // token index
    const size_t base = ((size_t)blockIdx.x * WAVES + w) * (T * D_MODEL);

    // ---- stage weights/params (256 threads, coalesced)
    if (tid < D_MODEL * D_MODEL) { sWq[tid] = Wq[tid]; sWk[tid] = Wk[tid]; sWv[tid] = Wv[tid]; }
    sW1[tid]       = W1[tid];
    sW1[tid + 256] = W1[tid + 256];
    sW2[tid]       = W2[tid];
    sW2[tid + 256] = W2[tid + 256];
    if (tid < D_MODEL) {
        sG1[tid] = ln1_g[tid]; sB1[tid] = ln1_b[tid];
        sG2[tid] = ln2_g[tid]; sB2[tid] = ln2_b[tid];
        sBF2[tid] = b2[tid];
    }
    if (tid >= 64 && tid < 64 + D_FF) sBF1[tid - 64] = b1[tid - 64];

    // ---- load this token's 16-float row
    float xr[D_MODEL];
    {
        const float4* xp = (const float4*)(x + base + (size_t)t * D_MODEL);
        float4 a = xp[0], b = xp[1], c = xp[2], d = xp[3];
        xr[0]=a.x; xr[1]=a.y; xr[2]=a.z;  xr[3]=a.w;
        xr[4]=b.x; xr[5]=b.y; xr[6]=b.z;  xr[7]=b.w;
        xr[8]=c.x; xr[9]=c.y; xr[10]=c.z; xr[11]=c.w;
        xr[12]=d.x;xr[13]=d.y;xr[14]=d.z; xr[15]=d.w;
    }

    // ---- LN1 stats (channel dim fully per-lane)
    float mu = 0.f;
    #pragma unroll
    for (int j = 0; j < D_MODEL; ++j) mu += xr[j];
    mu *= (1.f / D_MODEL);
    float var = 0.f;
    #pragma unroll
    for (int j = 0; j < D_MODEL; ++j) { float d = xr[j] - mu; var += d * d; }
    var *= (1.f / D_MODEL);
    float rstd = rsqrtf(var + EPS);

    __syncthreads();   // weights staged

    float h[D_MODEL];
    #pragma unroll
    for (int j = 0; j < D_MODEL; ++j)
        h[j] = (xr[j] - mu) * rstd * sG1[j] + sB1[j];

    // ---- projections: q in regs, k/v staged to LDS. Row-major weight rows
    //      are contiguous -> ds_read_b128 broadcasts.
    float q[D_MODEL], kk[D_MODEL], vv[D_MODEL];
    #pragma unroll
    for (int j = 0; j < D_MODEL; ++j) { q[j] = 0.f; kk[j] = 0.f; vv[j] = 0.f; }
    #pragma unroll
    for (int i = 0; i < D_MODEL; ++i) {
        const float hi = h[i];
        #pragma unroll
        for (int j = 0; j < D_MODEL; ++j) {
            q[j]  += hi * sWq[i*D_MODEL + j];
            kk[j] += hi * sWk[i*D_MODEL + j];
            vv[j] += hi * sWv[i*D_MODEL + j];
        }
    }
    {
        float4* kp = (float4*)&sK[w][t][0];
        float4* vp = (float4*)&sV[w][t][0];
        kp[0] = make_float4(kk[0],kk[1],kk[2],kk[3]);
        kp[1] = make_float4(kk[4],kk[5],kk[6],kk[7]);
        kp[2] = make_float4(kk[8],kk[9],kk[10],kk[11]);
        kp[3] = make_float4(kk[12],kk[13],kk[14],kk[15]);
        vp[0] = make_float4(vv[0],vv[1],vv[2],vv[3]);
        vp[1] = make_float4(vv[4],vv[5],vv[6],vv[7]);
        vp[2] = make_float4(vv[8],vv[9],vv[10],vv[11]);
        vp[3] = make_float4(vv[12],vv[13],vv[14],vv[15]);
    }
    // fold 1/sqrt(D) into q once
    #pragma unroll
    for (int j = 0; j < D_MODEL; ++j) q[j] *= 0.25f;

    __syncthreads();   // K/V visible

    // ---- causal attention, chunk-8 online softmax
    float m = -1e30f, l = 0.f;
    float y[D_MODEL];
    #pragma unroll
    for (int j = 0; j < D_MODEL; ++j) y[j] = 0.f;

    for (int c = 0; c < T / 8; ++c) {
        float sc[8];
        #pragma unroll
        for (int u = 0; u < 8; ++u) {
            const int s = c * 8 + u;
            const float4* kp = (const float4*)&sK[w][s][0];
            float4 k0 = kp[0], k1 = kp[1], k2 = kp[2], k3 = kp[3];
            float d = q[0]*k0.x + q[1]*k0.y + q[2]*k0.z + q[3]*k0.w
                    + q[4]*k1.x + q[5]*k1.y + q[6]*k1.z + q[7]*k1.w
                    + q[8]*k2.x + q[9]*k2.y + q[10]*k2.z + q[11]*k2.w
                    + q[12]*k3.x + q[13]*k3.y + q[14]*k3.z + q[15]*k3.w;
            sc[u] = (s <= t) ? d : -1e30f;
        }
        float cm = sc[0];
        #pragma unroll
        for (int u = 1; u < 8; ++u) cm = fmaxf(cm, sc[u]);
        float mn    = fmaxf(m, cm);
        float alpha = __expf(m - mn);
        l *= alpha;
        #pragma unroll
        for (int j = 0; j < D_MODEL; ++j) y[j] *= alpha;
        #pragma unroll
        for (int u = 0; u < 8; ++u) {
            const int s = c * 8 + u;
            float p = __expf(sc[u] - mn);
            l += p;
            const float4* vp = (const float4*)&sV[w][s][0];
            float4 v0 = vp[0], v1 = vp[1], v2 = vp[2], v3 = vp[3];
            y[0]  += p*v0.x; y[1]  += p*v0.y; y[2]  += p*v0.z; y[3]  += p*v0.w;
            y[4]  += p*v1.x; y[5]  += p*v1.y; y[6]  += p*v1.z; y[7]  += p*v1.w;
            y[8]  += p*v2.x; y[9]  += p*v2.y; y[10] += p*v2.z; y[11] += p*v2.w;
            y[12] += p*v3.x; y[13] += p*v3.y; y[14] += p*v3.z; y[15] += p*v3.w;
        }
        m = mn;
    }
    {
        float rl = fast_rcp(l);
        #pragma unroll
        for (int j = 0; j < D_MODEL; ++j) xr[j] += y[j] * rl;   // residual 1
    }

    // ---- LN2
    mu = 0.f;
    #pragma unroll
    for (int j = 0; j < D_MODEL; ++j) mu += xr[j];
    mu *= (1.f / D_MODEL);
    var = 0.f;
    #pragma unroll
    for (int j = 0; j < D_MODEL; ++j) { float d = xr[j] - mu; var += d * d; }
    var *= (1.f / D_MODEL);
    rstd = rsqrtf(var + EPS);

    float h2[D_MODEL];
    #pragma unroll
    for (int j = 0; j < D_MODEL; ++j)
        h2[j] = (xr[j] - mu) * rstd * sG2[j] + sB2[j];

    // ---- FFN: u = h2 @ W1 + b1 (accumulate all 32 in regs, W1 rows contiguous)
    float uf[D_FF];
    #pragma unroll
    for (int f = 0; f < D_FF; ++f) uf[f] = sBF1[f];
    #pragma unroll
    for (int j = 0; j < D_MODEL; ++j) {
        const float hj = h2[j];
        #pragma unroll
        for (int f = 0; f < D_FF; ++f) uf[f] += hj * sW1[j*D_FF + f];
    }
    float o[D_MODEL];
    #pragma unroll
    for (int j = 0; j < D_MODEL; ++j) o[j] = sBF2[j];
    #pragma unroll
    for (int f = 0; f < D_FF; ++f) {
        const float g = gelu_exact(uf[f]);
        #pragma unroll
        for (int j = 0; j < D_MODEL; ++j) o[j] += g * sW2[f*D_MODEL + j];
    }

    // ---- residual 2 + store
    {
        float4* op = (float4*)(out + base + (size_t)t * D_MODEL);
        op[0] = make_float4(xr[0]+o[0],   xr[1]+o[1],   xr[2]+o[2],   xr[3]+o[3]);
        op[1] = make_float4(xr[4]+o[4],   xr[5]+o[5],   xr[6]+o[6],   xr[7]+o[7]);
        op[2] = make_float4(xr[8]+o[8],   xr[9]+o[9],   xr[10]+o[10], xr[11]+o[11]);
        op[3] = make_float4(xr[12]+o[12], xr[13]+o[13], xr[14]+o[14], xr[15]+o[15]);
    }
}

extern "C" void kernel_launch(void* const* d_in, const int* in_sizes, int n_in,
                              void* d_out, int out_size, void* d_ws, size_t ws_size,
                              hipStream_t stream) {
    const float* x     = (const float*)d_in[0];
    const float* Wk    = (const float*)d_in[1];
    const float* Wq    = (const float*)d_in[2];
    const float* Wv    = (const float*)d_in[3];
    const float* ln1_g = (const float*)d_in[4];
    const float* ln1_b = (const float*)d_in[5];
    const float* ln2_g = (const float*)d_in[6];
    const float* ln2_b = (const float*)d_in[7];
    const float* W1    = (const float*)d_in[8];
    const float* b1    = (const float*)d_in[9];
    const float* W2    = (const float*)d_in[10];
    const float* b2    = (const float*)d_in[11];
    float* out = (float*)d_out;

    const int n_blocks = in_sizes[0] / (T * D_MODEL);   // 16384
    transformer_block_kernel<<<n_blocks / WAVES, 256, 0, stream>>>(
        x, Wk, Wq, Wv, ln1_g, ln1_b, ln2_g, ln2_b, W1, b1, W2, b2, out);
}

// Round 7
// 271.152 us; speedup vs baseline: 1.4278x; 1.0128x over previous
//
#include <hip/hip_runtime.h>
#include <hip/hip_bf16.h>
#include <math.h>

// ---------------------------------------------------------------------------
// Hybrid fused transformer block (R7 bisect):
//   - MFMA (split-3 bf16, fp32-grade) for Q/K/V projections, FFN1, FFN2
//   - SCALAR fp32 attention (R2-verbatim: lane=token, chunk-8 online softmax)
// One wave (64 threads) per batch block of 64 tokens x 16 channels.
// v_mfma_f32_16x16x32_bf16 layouts (m89/m91-verified):
//   C/D: col=lane&15, row=(lane>>4)*4+reg
//   A:   A[m=lane&15][k=(lane>>4)*8+j]
//   B:   B[k=(lane>>4)*8+j][n=lane&15]
// Only phase-level cross-lane LDS hand-offs, each guarded by __syncthreads().
// ---------------------------------------------------------------------------

typedef __attribute__((ext_vector_type(8))) short bf8;   // 8 bf16 (4 VGPRs)
typedef __attribute__((ext_vector_type(4))) float f4;    // 4 fp32 (C/D frag)

union FragU { uint4 u4; uint u[4]; bf8 b; };

__device__ __forceinline__ uint packbf(float lo, float hi) {   // v_cvt_pk_bf16_f32
    union { __hip_bfloat162 h; uint u; } c;
    c.h = __float22bfloat162_rn(make_float2(lo, hi));
    return c.u;
}
// split pair (a,b) into bf16-hi word + bf16-lo(residual) word
__device__ __forceinline__ void split2(float a, float b, uint& h, uint& l) {
    h = packbf(a, b);
    float ra = a - __uint_as_float(h << 16);          // exact residual
    float rb = b - __uint_as_float(h & 0xFFFF0000u);
    l = packbf(ra, rb);
}

// exact-gelu via A&S 7.1.26 erf (max err 1.5e-7), branch-free
__device__ __forceinline__ float gelu_f(float u) {
    float z  = fabsf(u) * 0.70710678118654752f;
    float tt = __builtin_amdgcn_rcpf(1.f + 0.3275911f * z);
    float poly = ((((1.061405429f * tt - 1.453152027f) * tt + 1.421413741f) * tt
                   - 0.284496736f) * tt + 0.254829592f) * tt;
    float erfz = 1.f - poly * __expf(-z * z);
    return 0.5f * u * (1.f + copysignf(erfz, u));
}

#define MFMA(a, b, c) __builtin_amdgcn_mfma_f32_16x16x32_bf16(a, b, c, 0, 0, 0)

// LDS arena (uint/float units), 3328 words = 13312 B.
//  Phase A: sQ f32[64][20]@0, sK f32[64][16]@1280, sV f32[64][16]@2304
//  Phase C: sH2 bf16 hi+lo [64][20]@0        (over dead sQ; per-lane rows)
//  Phase D: sU  bf16 hi+lo [64][36]@0        (over dead sH2/sK)
//  Phase E: sFFN f32[64][17]@0               (over dead sU head)
#define O_SQ   0
#define O_SK   1280
#define O_SV   2304
#define O_SH2  0
#define O_SU   0
#define O_SFFN 0
#define ARENA  3328

// hi/lo split B-fragment pair: B[k=kb+j][n], row-major W, leading dim ld
__device__ __forceinline__ void loadWfragHL(const float* __restrict__ W, int ld,
                                            int n, int kb, bool valid, float scale,
                                            bf8& hf, bf8& lf) {
    FragU H, L;
    if (valid) {
        #pragma unroll
        for (int p = 0; p < 4; ++p) {
            float a = W[(kb+2*p  )*ld+n]*scale;
            float b = W[(kb+2*p+1)*ld+n]*scale;
            split2(a, b, H.u[p], L.u[p]);
        }
    } else {
        H.u4 = make_uint4(0u,0u,0u,0u);
        L.u4 = H.u4;
    }
    hf = H.b; lf = L.b;
}

__global__ __launch_bounds__(64, 3)
void tb_kernel(const float* __restrict__ x,
               const float* __restrict__ Wk, const float* __restrict__ Wq,
               const float* __restrict__ Wv,
               const float* __restrict__ ln1g, const float* __restrict__ ln1b,
               const float* __restrict__ ln2g, const float* __restrict__ ln2b,
               const float* __restrict__ W1, const float* __restrict__ b1,
               const float* __restrict__ W2, const float* __restrict__ b2,
               float* __restrict__ out)
{
    __shared__ __align__(16) uint lds[ARENA];
    float* ldsF = (float*)lds;
    const int lane = threadIdx.x;
    const int c15  = lane & 15;
    const int quad = lane >> 4;
    const size_t base = (size_t)blockIdx.x * (64 * 16);
    const f4 z4 = {0.f, 0.f, 0.f, 0.f};
    const bool kv = (quad < 2);          // K=16 mats: only quads 0,1 carry data
    const int  kb = quad * 8;

    // ---- attention weight fragments (split-3)
    bf8 fWq_h, fWq_l, fWk_h, fWk_l, fWv_h, fWv_l;
    loadWfragHL(Wq, 16, c15, kb, kv, 0.25f, fWq_h, fWq_l);  // fold 1/sqrt(D)
    loadWfragHL(Wk, 16, c15, kb, kv, 1.0f,  fWk_h, fWk_l);
    loadWfragHL(Wv, 16, c15, kb, kv, 1.0f,  fWv_h, fWv_l);

    // ---- LN1 (fp32) -> split hi/lo A-fragments
    bf8 ah_h[4], ah_l[4];
    {
        float gg[8], bb[8];
        if (kv) {
            const float4* gp = (const float4*)(ln1g + kb);
            const float4* bp = (const float4*)(ln1b + kb);
            float4 g0 = gp[0], g1 = gp[1], b0 = bp[0], b1_ = bp[1];
            gg[0]=g0.x; gg[1]=g0.y; gg[2]=g0.z; gg[3]=g0.w;
            gg[4]=g1.x; gg[5]=g1.y; gg[6]=g1.z; gg[7]=g1.w;
            bb[0]=b0.x; bb[1]=b0.y; bb[2]=b0.z; bb[3]=b0.w;
            bb[4]=b1_.x; bb[5]=b1_.y; bb[6]=b1_.z; bb[7]=b1_.w;
        }
        #pragma unroll
        for (int mt = 0; mt < 4; ++mt) {
            FragU Ah, Al;
            if (kv) {
                const float4* xp = (const float4*)(x + base + (size_t)(mt*16 + c15)*16 + kb);
                float4 v0 = xp[0], v1 = xp[1];
                float xs[8] = {v0.x,v0.y,v0.z,v0.w, v1.x,v1.y,v1.z,v1.w};
                float s = 0.f, s2 = 0.f;
                #pragma unroll
                for (int j = 0; j < 8; ++j) { s += xs[j]; s2 += xs[j]*xs[j]; }
                s  += __shfl_xor(s, 16);    // combine half-rows (both in quads 0,1)
                s2 += __shfl_xor(s2, 16);
                float mu   = s * 0.0625f;
                float var  = s2 * 0.0625f - mu*mu;
                float rstd = rsqrtf(var + 1e-5f);
                float h[8];
                #pragma unroll
                for (int j = 0; j < 8; ++j) h[j] = (xs[j]-mu)*rstd*gg[j] + bb[j];
                #pragma unroll
                for (int p = 0; p < 4; ++p) split2(h[2*p], h[2*p+1], Ah.u[p], Al.u[p]);
            } else {
                Ah.u4 = make_uint4(0u,0u,0u,0u);
                Al.u4 = Ah.u4;
            }
            ah_h[mt] = Ah.b; ah_l[mt] = Al.b;
        }
    }

    // ---- projections (split-3): Q,K,V stored fp32 row-major [token][ch]
    #pragma unroll
    for (int mt = 0; mt < 4; ++mt) {
        f4 qc = MFMA(ah_l[mt], fWq_h, z4);
        qc = MFMA(ah_h[mt], fWq_l, qc);
        qc = MFMA(ah_h[mt], fWq_h, qc);
        f4 kc = MFMA(ah_l[mt], fWk_h, z4);
        kc = MFMA(ah_h[mt], fWk_l, kc);
        kc = MFMA(ah_h[mt], fWk_h, kc);
        f4 vc = MFMA(ah_l[mt], fWv_h, z4);
        vc = MFMA(ah_h[mt], fWv_l, vc);
        vc = MFMA(ah_h[mt], fWv_h, vc);
        const int rowb = mt*16 + quad*4;
        #pragma unroll
        for (int r = 0; r < 4; ++r) {
            ldsF[O_SQ + (rowb + r)*20 + c15] = qc[r];
            ldsF[O_SK + (rowb + r)*16 + c15] = kc[r];
            ldsF[O_SV + (rowb + r)*16 + c15] = vc[r];
        }
    }
    __syncthreads();   // B1: Q/K/V visible

    // ---- SCALAR attention (R2-proven): lane = token t
    float qr[16];
    {
        const float4* qp = (const float4*)(ldsF + O_SQ + lane*20);  // 80B rows, aligned
        float4 a = qp[0], b = qp[1], c = qp[2], d = qp[3];
        qr[0]=a.x; qr[1]=a.y; qr[2]=a.z;  qr[3]=a.w;
        qr[4]=b.x; qr[5]=b.y; qr[6]=b.z;  qr[7]=b.w;
        qr[8]=c.x; qr[9]=c.y; qr[10]=c.z; qr[11]=c.w;
        qr[12]=d.x;qr[13]=d.y;qr[14]=d.z; qr[15]=d.w;
    }
    float xs[16];
    {
        const float4* xp = (const float4*)(x + base + (size_t)lane * 16);
        float4 a = xp[0], b = xp[1], c = xp[2], d = xp[3];
        xs[0]=a.x; xs[1]=a.y; xs[2]=a.z;  xs[3]=a.w;
        xs[4]=b.x; xs[5]=b.y; xs[6]=b.z;  xs[7]=b.w;
        xs[8]=c.x; xs[9]=c.y; xs[10]=c.z; xs[11]=c.w;
        xs[12]=d.x;xs[13]=d.y;xs[14]=d.z; xs[15]=d.w;
    }

    float m = -1e30f, l = 0.f;
    float y[16];
    #pragma unroll
    for (int j = 0; j < 16; ++j) y[j] = 0.f;

    for (int c = 0; c < 8; ++c) {
        float sc[8];
        #pragma unroll
        for (int u = 0; u < 8; ++u) {
            const int s = c * 8 + u;
            const float4* kp = (const float4*)(ldsF + O_SK + s*16);  // broadcast
            float4 k0 = kp[0], k1 = kp[1], k2 = kp[2], k3 = kp[3];
            float d = qr[0]*k0.x + qr[1]*k0.y + qr[2]*k0.z + qr[3]*k0.w
                    + qr[4]*k1.x + qr[5]*k1.y + qr[6]*k1.z + qr[7]*k1.w
                    + qr[8]*k2.x + qr[9]*k2.y + qr[10]*k2.z + qr[11]*k2.w
                    + qr[12]*k3.x + qr[13]*k3.y + qr[14]*k3.z + qr[15]*k3.w;
            sc[u] = (s <= lane) ? d : -1e30f;     // causal (scale folded in Wq)
        }
        float cm = sc[0];
        #pragma unroll
        for (int u = 1; u < 8; ++u) cm = fmaxf(cm, sc[u]);
        float mn    = fmaxf(m, cm);
        float alpha = __expf(m - mn);
        l *= alpha;
        #pragma unroll
        for (int j = 0; j < 16; ++j) y[j] *= alpha;
        #pragma unroll
        for (int u = 0; u < 8; ++u) {
            const int s = c * 8 + u;
            float p = __expf(sc[u] - mn);
            l += p;
            const float4* vp = (const float4*)(ldsF + O_SV + s*16);  // broadcast
            float4 v0 = vp[0], v1 = vp[1], v2 = vp[2], v3 = vp[3];
            y[0]  += p*v0.x; y[1]  += p*v0.y; y[2]  += p*v0.z; y[3]  += p*v0.w;
            y[4]  += p*v1.x; y[5]  += p*v1.y; y[6]  += p*v1.z; y[7]  += p*v1.w;
            y[8]  += p*v2.x; y[9]  += p*v2.y; y[10] += p*v2.z; y[11] += p*v2.w;
            y[12] += p*v3.x; y[13] += p*v3.y; y[14] += p*v3.z; y[15] += p*v3.w;
        }
        m = mn;
    }
    float x2[16];
    {
        float rl = __builtin_amdgcn_rcpf(l);
        #pragma unroll
        for (int j = 0; j < 16; ++j) x2[j] = xs[j] + y[j] * rl;   // residual 1
    }

    // ---- LN2 fully per-lane -> h2 split -> sH2 (over dead sQ; same-lane rows)
    {
        float s = 0.f, s2 = 0.f;
        #pragma unroll
        for (int j = 0; j < 16; ++j) { s += x2[j]; s2 += x2[j]*x2[j]; }
        float mu   = s * 0.0625f;
        float var  = s2 * 0.0625f - mu*mu;
        float rstd = rsqrtf(var + 1e-5f);
        uint hh[8], hl[8];
        #pragma unroll
        for (int jj = 0; jj < 4; ++jj) {
            float4 gv = ((const float4*)ln2g)[jj];
            float4 bv = ((const float4*)ln2b)[jj];
            float h0 = (x2[4*jj+0]-mu)*rstd*gv.x + bv.x;
            float h1 = (x2[4*jj+1]-mu)*rstd*gv.y + bv.y;
            float h2v = (x2[4*jj+2]-mu)*rstd*gv.z + bv.z;
            float h3 = (x2[4*jj+3]-mu)*rstd*gv.w + bv.w;
            split2(h0, h1, hh[2*jj],   hl[2*jj]);
            split2(h2v, h3, hh[2*jj+1], hl[2*jj+1]);
        }
        *(uint4*)(lds + O_SH2 + lane*20)      = make_uint4(hh[0],hh[1],hh[2],hh[3]);
        *(uint4*)(lds + O_SH2 + lane*20 + 4)  = make_uint4(hh[4],hh[5],hh[6],hh[7]);
        *(uint4*)(lds + O_SH2 + lane*20 + 8)  = make_uint4(hl[0],hl[1],hl[2],hl[3]);
        *(uint4*)(lds + O_SH2 + lane*20 + 12) = make_uint4(hl[4],hl[5],hl[6],hl[7]);
    }
    __syncthreads();   // B2: sH2 visible

    // ---- h2 A-fragments
    bf8 a2h[4], a2l[4];
    #pragma unroll
    for (int i = 0; i < 4; ++i) {
        FragU H, L;
        if (kv) {
            H.u4 = *(const uint4*)(lds + O_SH2 + (i*16 + c15)*20 + quad*4);
            L.u4 = *(const uint4*)(lds + O_SH2 + (i*16 + c15)*20 + 8 + quad*4);
        } else {
            H.u4 = make_uint4(0u,0u,0u,0u);
            L.u4 = H.u4;
        }
        a2h[i] = H.b; a2l[i] = L.b;
    }
    __syncthreads();   // B3: sH2 dead; sU region writable

    // ---- FFN weight fragments
    bf8 fW1a_h, fW1a_l, fW1b_h, fW1b_l, fW2_h, fW2_l;
    loadWfragHL(W1, 32, c15,      kb, kv,   1.0f, fW1a_h, fW1a_l);
    loadWfragHL(W1, 32, c15 + 16, kb, kv,   1.0f, fW1b_h, fW1b_l);
    loadWfragHL(W2, 16, c15,      kb, true, 1.0f, fW2_h,  fW2_l);

    // ---- FFN1 (split-3) + gelu -> sU hi/lo [64][36]
    {
        float bu0 = b1[c15], bu1 = b1[16 + c15];
        f4 cb0 = {bu0, bu0, bu0, bu0};
        f4 cb1 = {bu1, bu1, bu1, bu1};
        f4 uu[4][2];
        #pragma unroll
        for (int mt = 0; mt < 4; ++mt) {
            f4 u0 = MFMA(a2l[mt], fW1a_h, cb0);
            u0 = MFMA(a2h[mt], fW1a_l, u0);
            uu[mt][0] = MFMA(a2h[mt], fW1a_h, u0);
            f4 u1 = MFMA(a2l[mt], fW1b_h, cb1);
            u1 = MFMA(a2h[mt], fW1b_l, u1);
            uu[mt][1] = MFMA(a2h[mt], fW1b_h, u1);
        }
        const bool wr = ((c15 & 1) == 0);
        #pragma unroll
        for (int mt = 0; mt < 4; ++mt)
            #pragma unroll
            for (int nt = 0; nt < 2; ++nt)
                #pragma unroll
                for (int r = 0; r < 4; ++r) {
                    float g  = gelu_f(uu[mt][nt][r]);
                    float go = __shfl_xor(g, 1);
                    if (wr) {
                        uint hw, lw;
                        split2(g, go, hw, lw);
                        uint row = mt*16 + quad*4 + r;
                        lds[O_SU + row*36 +      nt*8 + (c15 >> 1)] = hw;
                        lds[O_SU + row*36 + 16 + nt*8 + (c15 >> 1)] = lw;
                    }
                }
    }
    __syncthreads();   // B4: sU visible

    // ---- FFN2 (split-3, K=32 full)
    f4 fo[4];
    {
        float bo = b2[c15];
        f4 cb = {bo, bo, bo, bo};
        #pragma unroll
        for (int mt = 0; mt < 4; ++mt) {
            FragU H, L;
            uint off = (uint)(mt*16 + c15)*36;
            H.u4 = *(const uint4*)(lds + O_SU + off +      quad*4);
            L.u4 = *(const uint4*)(lds + O_SU + off + 16 + quad*4);
            f4 f0 = MFMA(L.b, fW2_h, cb);
            f0 = MFMA(H.b, fW2_l, f0);
            fo[mt] = MFMA(H.b, fW2_h, f0);
        }
    }
    __syncthreads();   // B5: sU dead; sFFN writable
    #pragma unroll
    for (int mt = 0; mt < 4; ++mt)
        #pragma unroll
        for (int r = 0; r < 4; ++r)
            lds[O_SFFN + (mt*16 + quad*4 + r)*17 + c15] = __float_as_uint(fo[mt][r]);
    __syncthreads();   // B6: sFFN visible

    // ---- final residual + coalesced store
    {
        float4 o[4];
        #pragma unroll
        for (int jj = 0; jj < 4; ++jj) {
            o[jj].x = x2[4*jj+0] + __uint_as_float(lds[O_SFFN + lane*17 + 4*jj+0]);
            o[jj].y = x2[4*jj+1] + __uint_as_float(lds[O_SFFN + lane*17 + 4*jj+1]);
            o[jj].z = x2[4*jj+2] + __uint_as_float(lds[O_SFFN + lane*17 + 4*jj+2]);
            o[jj].w = x2[4*jj+3] + __uint_as_float(lds[O_SFFN + lane*17 + 4*jj+3]);
        }
        float4* op = (float4*)(out + base + (size_t)lane * 16);
        op[0] = o[0]; op[1] = o[1]; op[2] = o[2]; op[3] = o[3];
    }
}

extern "C" void kernel_launch(void* const* d_in, const int* in_sizes, int n_in,
                              void* d_out, int out_size, void* d_ws, size_t ws_size,
                              hipStream_t stream) {
    const float* x     = (const float*)d_in[0];
    const float* Wk    = (const float*)d_in[1];
    const float* Wq    = (const float*)d_in[2];
    const float* Wv    = (const float*)d_in[3];
    const float* ln1_g = (const float*)d_in[4];
    const float* ln1_b = (const float*)d_in[5];
    const float* ln2_g = (const float*)d_in[6];
    const float* ln2_b = (const float*)d_in[7];
    const float* W1    = (const float*)d_in[8];
    const float* b1    = (const float*)d_in[9];
    const float* W2    = (const float*)d_in[10];
    const float* b2    = (const float*)d_in[11];
    float* out = (float*)d_out;

    const int n_blocks = in_sizes[0] / (64 * 16);   // 16384
    tb_kernel<<<n_blocks, 64, 0, stream>>>(
        x, Wk, Wq, Wv, ln1_g, ln1_b, ln2_g, ln2_b, W1, b1, W2, b2, out);
}